// Round 5
// baseline (99.829 us; speedup 1.0000x reference)
//
#include <hip/hip_runtime.h>

// Analytic collapse (verified R1/R2, absmax 9.8e-4):
//   <Z_0> = c1*c2*...*c7,  <Z_j> = c0*...*cj,  c_j = cos(t_j + theta_j)
// Block = 64 consecutive tokens (8 octets) of one batch; 512 threads (8 waves).
// Token-per-lane: lane t holds x[t][0..63] in VGPRs; W rows stream as
// wave-uniform (scalar) loads -> inner loops are pure v_fma, no LDS per FMA.
// Phase 1: wave wg does 3 (matrix,head) pairs p=3*wg+pp (24 total = 3 mat x 8 heads).
// Phase 2: wave wg does tokens 8wg..8wg+7 (R2's verified 8x8 head-mix attention).
// Phase 3: wave wg does output cols e=8wg..8wg+7, lane = scrambled row.
// LDS layouts keep the LANE-varying index element-contiguous => <=2-way (free).

#define XS 66   // sX  [t][XS]  stride (b64 reads conflict-free)
#define ZS 65   // sZ  [e][ZS]  + t    (b32, lane-contiguous t)
#define CS 65   // sScr/sOut [col][CS] + row

__global__ __launch_bounds__(512)
void qattn_fused(const float* __restrict__ xg,
                 const float* __restrict__ wqg, const float* __restrict__ wkg,
                 const float* __restrict__ wvg, const float* __restrict__ wog,
                 const float* __restrict__ thg,
                 float* __restrict__ outg)
{
    __shared__ float sX[64 * XS];     // 16.9 KB
    __shared__ float sZ[192 * ZS];    // 49.9 KB  q,k,v expectations [m*64+e][t]
    __shared__ float sScr[64 * CS];   // 16.6 KB  scrambled [col][row]
    __shared__ float sOut[64 * CS];   // 16.6 KB  output    [e][row]

    const int tid  = threadIdx.x;
    const int lane = tid & 63;
    const int wg   = tid >> 6;        // 0..7
    const int b    = blockIdx.x >> 3;
    const int g    = blockIdx.x & 7;  // 64-token group within batch row

    // ---- stage x (64 tokens x 64 floats), coalesced global -> LDS ----
    const float* xbase = xg + (size_t)(b * 512 + g * 64) * 64;
    #pragma unroll
    for (int rep = 0; rep < 2; ++rep) {
        const int f4 = tid + rep * 512;            // float4 index 0..1023
        const float4 v = ((const float4*)xbase)[f4];
        const int t = f4 >> 4, c = (f4 & 15) * 4;
        float* d = &sX[t * XS + c];
        ((float2*)d)[0] = make_float2(v.x, v.y);
        ((float2*)d)[1] = make_float2(v.z, v.w);
    }
    __syncthreads();

    // ---- per-lane x row (lane = token); b64 stride-66: conflict-free ----
    float xr[64];
    #pragma unroll
    for (int c = 0; c < 32; ++c) {
        const float2 v = *(const float2*)&sX[lane * XS + c * 2];
        xr[2 * c] = v.x; xr[2 * c + 1] = v.y;
    }
    float th[8];
    #pragma unroll
    for (int j = 0; j < 8; ++j) th[j] = thg[j];

    // ---- phase 1: projections, (matrix m, head h) pairs; scalar W stream ----
    #pragma unroll
    for (int pp = 0; pp < 3; ++pp) {
        const int p = wg * 3 + pp;                 // 0..23
        const int m = p >> 3, h = p & 7;
        const float* wm = (m == 0) ? wqg : (m == 1) ? wkg : wvg;
        float cj[8];
        #pragma unroll
        for (int j = 0; j < 8; ++j) {
            const float* wr = wm + (h * 8 + j) * 64;   // wave-uniform address
            float a0 = 0.f, a1 = 0.f, a2 = 0.f, a3 = 0.f;
            #pragma unroll
            for (int kc = 0; kc < 4; ++kc) {
                const float4 w0 = *(const float4*)(wr + kc * 16);
                const float4 w1 = *(const float4*)(wr + kc * 16 + 4);
                const float4 w2 = *(const float4*)(wr + kc * 16 + 8);
                const float4 w3 = *(const float4*)(wr + kc * 16 + 12);
                const int k = kc * 16;
                a0 = fmaf(w0.x, xr[k+ 0], a0); a0 = fmaf(w0.y, xr[k+ 1], a0);
                a0 = fmaf(w0.z, xr[k+ 2], a0); a0 = fmaf(w0.w, xr[k+ 3], a0);
                a1 = fmaf(w1.x, xr[k+ 4], a1); a1 = fmaf(w1.y, xr[k+ 5], a1);
                a1 = fmaf(w1.z, xr[k+ 6], a1); a1 = fmaf(w1.w, xr[k+ 7], a1);
                a2 = fmaf(w2.x, xr[k+ 8], a2); a2 = fmaf(w2.y, xr[k+ 9], a2);
                a2 = fmaf(w2.z, xr[k+10], a2); a2 = fmaf(w2.w, xr[k+11], a2);
                a3 = fmaf(w3.x, xr[k+12], a3); a3 = fmaf(w3.y, xr[k+13], a3);
                a3 = fmaf(w3.z, xr[k+14], a3); a3 = fmaf(w3.w, xr[k+15], a3);
            }
            cj[j] = cosf(((a0 + a1) + (a2 + a3)) + th[j]);
        }
        // lane-local prefix products
        float z[8];
        z[1] = cj[0] * cj[1];
        z[2] = z[1] * cj[2];  z[3] = z[2] * cj[3];
        z[4] = z[3] * cj[4];  z[5] = z[4] * cj[5];
        z[6] = z[5] * cj[6];  z[7] = z[6] * cj[7];
        float z0 = cj[1] * cj[2];
        z0 *= cj[3]; z0 *= cj[4]; z0 *= cj[5]; z0 *= cj[6]; z0 *= cj[7];
        z[0] = z0;
        const int zb = (m * 64 + h * 8) * ZS + lane;   // lane-contiguous writes
        #pragma unroll
        for (int j = 0; j < 8; ++j) sZ[zb + j * ZS] = z[j];
    }
    __syncthreads();

    // ---- phase 2: per-token 8x8 head-mixing attention; tokens 8wg..8wg+7 ----
    {
        const int ii = lane >> 3, jj = lane & 7;
        #pragma unroll
        for (int u = 0; u < 8; ++u) {
            const int t = wg * 8 + u;               // wave-uniform
            float sc = 0.f;
            #pragma unroll
            for (int w = 0; w < 8; ++w)
                sc = fmaf(sZ[(ii * 8 + w) * ZS + t],
                          sZ[(64 + jj * 8 + w) * ZS + t], sc);
            sc *= 0.35355339059327373f;             // 1/sqrt(8)
            float mx = sc;
            mx = fmaxf(mx, __shfl_xor(mx, 1));
            mx = fmaxf(mx, __shfl_xor(mx, 2));
            mx = fmaxf(mx, __shfl_xor(mx, 4));
            const float ex = expf(sc - mx);
            float sum = ex;
            sum += __shfl_xor(sum, 1);
            sum += __shfl_xor(sum, 2);
            sum += __shfl_xor(sum, 4);
            const float a = ex / sum;               // attn[t][ii][jj]
            float o = 0.f;                          // out[t][ii][w=jj]
            #pragma unroll
            for (int j2 = 0; j2 < 8; ++j2) {
                const float aj = __shfl(a, (lane & ~7) + j2);
                o = fmaf(aj, sZ[(128 + j2 * 8 + jj) * ZS + t], o);
            }
            // scrambled: local row r = ii*8 + (t>>3), col = 8*(t&7) + jj
            sScr[(8 * (t & 7) + jj) * CS + (ii * 8 + (t >> 3))] = o;
        }
    }
    __syncthreads();

    // ---- phase 3: out[r][e] = scr_row . Wo[e]; lane = row, e = 8wg..8wg+7 ----
    {
        float sr[64];
        #pragma unroll
        for (int k = 0; k < 64; ++k)
            sr[k] = sScr[k * CS + lane];            // lane-contiguous: free
        #pragma unroll
        for (int e8 = 0; e8 < 8; ++e8) {
            const float* wr = wog + (wg * 8 + e8) * 64;   // wave-uniform
            float a0 = 0.f, a1 = 0.f, a2 = 0.f, a3 = 0.f;
            #pragma unroll
            for (int kc = 0; kc < 4; ++kc) {
                const float4 w0 = *(const float4*)(wr + kc * 16);
                const float4 w1 = *(const float4*)(wr + kc * 16 + 4);
                const float4 w2 = *(const float4*)(wr + kc * 16 + 8);
                const float4 w3 = *(const float4*)(wr + kc * 16 + 12);
                const int k = kc * 16;
                a0 = fmaf(w0.x, sr[k+ 0], a0); a0 = fmaf(w0.y, sr[k+ 1], a0);
                a0 = fmaf(w0.z, sr[k+ 2], a0); a0 = fmaf(w0.w, sr[k+ 3], a0);
                a1 = fmaf(w1.x, sr[k+ 4], a1); a1 = fmaf(w1.y, sr[k+ 5], a1);
                a1 = fmaf(w1.z, sr[k+ 6], a1); a1 = fmaf(w1.w, sr[k+ 7], a1);
                a2 = fmaf(w2.x, sr[k+ 8], a2); a2 = fmaf(w2.y, sr[k+ 9], a2);
                a2 = fmaf(w2.z, sr[k+10], a2); a2 = fmaf(w2.w, sr[k+11], a2);
                a3 = fmaf(w3.x, sr[k+12], a3); a3 = fmaf(w3.y, sr[k+13], a3);
                a3 = fmaf(w3.z, sr[k+14], a3); a3 = fmaf(w3.w, sr[k+15], a3);
            }
            sOut[(wg * 8 + e8) * CS + lane] = (a0 + a1) + (a2 + a3);
        }
    }
    __syncthreads();

    // ---- final coalesced store: thread -> (row r, 8 cols) ----
    {
        const int r  = tid >> 3;                    // local row 0..63
        const int e0 = (tid & 7) * 8;
        const int R  = (r >> 3) * 64 + g * 8 + (r & 7);   // 64*head + octet
        float4 A, B2;
        A.x  = sOut[(e0 + 0) * CS + r]; A.y  = sOut[(e0 + 1) * CS + r];
        A.z  = sOut[(e0 + 2) * CS + r]; A.w  = sOut[(e0 + 3) * CS + r];
        B2.x = sOut[(e0 + 4) * CS + r]; B2.y = sOut[(e0 + 5) * CS + r];
        B2.z = sOut[(e0 + 6) * CS + r]; B2.w = sOut[(e0 + 7) * CS + r];
        float* orow = outg + ((size_t)(b * 512 + R) * 64 + e0);
        *(float4*)orow       = A;
        *(float4*)(orow + 4) = B2;
    }
}

extern "C" void kernel_launch(void* const* d_in, const int* in_sizes, int n_in,
                              void* d_out, int out_size, void* d_ws, size_t ws_size,
                              hipStream_t stream) {
    const float* x  = (const float*)d_in[0];
    const float* wq = (const float*)d_in[1];
    const float* wk = (const float*)d_in[2];
    const float* wv = (const float*)d_in[3];
    const float* wo = (const float*)d_in[4];
    const float* th = (const float*)d_in[5];
    float* out = (float*)d_out;
    // B=16, S=512: 16 batches x 8 sixty-four-token groups = 128 blocks
    qattn_fused<<<dim3(128), dim3(512), 0, stream>>>(x, wq, wk, wv, wo, th, out);
}

// Round 6
// 79.446 us; speedup vs baseline: 1.2566x; 1.2566x over previous
//
#include <hip/hip_runtime.h>

// Analytic collapse (verified R1/R2, absmax 9.8e-4):
//   <Z_0> = c1*...*c7,  <Z_j> = c0*...*cj,  c_j = cos(t_j + theta_j)
// R2 macro-structure (fastest so far): 1024 blocks x 256 thr, block = one
// batch/octet (8 tokens). All 4 waves: phase 1 projects 2 tokens x 3 matrices
// (lane = out elem e), phase 2 wave-local 8x8 head-mix attention on the same
// tokens, phase 3 fused Wo GEMM (2 heads/wave). Fix vs R2: W stored TRANSPOSED
// k-pair-interleaved in LDS (sWt[kk][2e+(k&1)]) so W reads are ds_read_b64
// lane-stride-2 (<=4-way, ~free) instead of stride-68 b128 (8-way, 2.94x).
// x broadcast via v_readlane (literal lanes from full unroll).

#define PS   130            // dwords per k-pair row (2*64 + 2 pad)
#define WT_M (32 * PS)      // dwords per matrix (4160)

__device__ __forceinline__ float rl(float v, int l) {
    return __int_as_float(__builtin_amdgcn_readlane(__float_as_int(v), l));
}

// segmented (8-lane) product scan -> <Z_w>; j = lane&7 (validated R1/R2)
__device__ __forceinline__ float expect_z(float ang, int j, int lane) {
    const float c = cosf(ang);
    float d = (j == 0) ? 1.f : c;
    float s;
    s = __shfl_up(d, 1); if (j >= 1) d *= s;
    s = __shfl_up(d, 2); if (j >= 2) d *= s;
    s = __shfl_up(d, 4); if (j >= 4) d *= s;
    const float c0 = __shfl(c, lane & ~7);   // c at j=0
    const float pf = __shfl(d, lane | 7);    // prod c1..c7
    return (j == 0) ? pf : c0 * d;
}

__global__ __launch_bounds__(256, 4)
void qattn_fused(const float* __restrict__ xg,
                 const float* __restrict__ wqg, const float* __restrict__ wkg,
                 const float* __restrict__ wvg, const float* __restrict__ wog,
                 const float* __restrict__ thg,
                 float* __restrict__ outg)
{
    __shared__ float sWt[4 * WT_M];      // 66.6 KB transposed W (q,k,v,o)
    __shared__ float sP[4][3][2][64];    // wave-local q,k,v expectations (6 KB)
    __shared__ float sScr[8 * 68];       // scrambled rows [h][col] (2.2 KB)

    const int tid  = threadIdx.x;
    const int lane = tid & 63;
    const int wg   = tid >> 6;
    const int b    = blockIdx.x >> 6;
    const int sg   = blockIdx.x & 63;
    const int t0   = wg * 2;

    // ---- stage W transposed: global [e][k] -> sWt[m][k>>1][2e + (k&1)] ----
    {
        const float* gm[4] = {wqg, wkg, wvg, wog};
        #pragma unroll
        for (int m = 0; m < 4; ++m) {
            #pragma unroll
            for (int r = 0; r < 4; ++r) {
                const int g = tid + 256 * r;        // float4 idx 0..1023
                const float4 v = ((const float4*)gm[m])[g];
                const int e = g >> 4, kq = g & 15;  // k = 4kq..4kq+3
                float* d = &sWt[m * WT_M + (2 * kq) * PS + 2 * e];
                *(float2*)d        = make_float2(v.x, v.y);   // kk=2kq
                *(float2*)(d + PS) = make_float2(v.z, v.w);   // kk=2kq+1
            }
        }
    }
    // x rows for this wave's 2 tokens (coalesced 256 B loads)
    const float* xb = xg + (size_t)(b * 512 + sg * 8 + t0) * 64;
    const float xr0 = xb[lane];
    const float xr1 = xb[64 + lane];
    const float thf = thg[lane & 7];
    __syncthreads();

    // ---- phase 1: 2 tokens x 3 matrices; lane = out elem e ----
    float aq0 = 0.f, aq1 = 0.f, ak0 = 0.f, ak1 = 0.f, av0 = 0.f, av1 = 0.f;
    {
        const float* wq2 = &sWt[0 * WT_M + 2 * lane];
        const float* wk2 = &sWt[1 * WT_M + 2 * lane];
        const float* wv2 = &sWt[2 * WT_M + 2 * lane];
        #pragma unroll
        for (int kk = 0; kk < 32; ++kk) {
            const float2 q2 = *(const float2*)(wq2 + kk * PS);
            const float2 k2 = *(const float2*)(wk2 + kk * PS);
            const float2 v2 = *(const float2*)(wv2 + kk * PS);
            const float xa0 = rl(xr0, 2 * kk), xa1 = rl(xr0, 2 * kk + 1);
            const float xb0 = rl(xr1, 2 * kk), xb1 = rl(xr1, 2 * kk + 1);
            aq0 = fmaf(q2.x, xa0, aq0); aq0 = fmaf(q2.y, xa1, aq0);
            aq1 = fmaf(q2.x, xb0, aq1); aq1 = fmaf(q2.y, xb1, aq1);
            ak0 = fmaf(k2.x, xa0, ak0); ak0 = fmaf(k2.y, xa1, ak0);
            ak1 = fmaf(k2.x, xb0, ak1); ak1 = fmaf(k2.y, xb1, ak1);
            av0 = fmaf(v2.x, xa0, av0); av0 = fmaf(v2.y, xa1, av0);
            av1 = fmaf(v2.x, xb0, av1); av1 = fmaf(v2.y, xb1, av1);
        }
    }
    {
        const int j = lane & 7;
        sP[wg][0][0][lane] = expect_z(aq0 + thf, j, lane);
        sP[wg][0][1][lane] = expect_z(aq1 + thf, j, lane);
        sP[wg][1][0][lane] = expect_z(ak0 + thf, j, lane);
        sP[wg][1][1][lane] = expect_z(ak1 + thf, j, lane);
        sP[wg][2][0][lane] = expect_z(av0 + thf, j, lane);
        sP[wg][2][1][lane] = expect_z(av1 + thf, j, lane);
    }

    // ---- phase 2: per-token 8x8 head-mix attention (wave-local, no barrier) ----
    {
        const int i = lane >> 3, j = lane & 7;
        #pragma unroll
        for (int u = 0; u < 2; ++u) {
            const int t = t0 + u;                   // local token 0..7
            const float* q  = sP[wg][0][u];
            const float* kk = sP[wg][1][u];
            const float* vv = sP[wg][2][u];
            float sc = 0.f;
            #pragma unroll
            for (int w = 0; w < 8; ++w)
                sc = fmaf(q[i * 8 + w], kk[j * 8 + w], sc);
            sc *= 0.35355339059327373f;             // 1/sqrt(8)
            float m = sc;
            m = fmaxf(m, __shfl_xor(m, 1));
            m = fmaxf(m, __shfl_xor(m, 2));
            m = fmaxf(m, __shfl_xor(m, 4));
            const float ex = expf(sc - m);
            float sum = ex;
            sum += __shfl_xor(sum, 1);
            sum += __shfl_xor(sum, 2);
            sum += __shfl_xor(sum, 4);
            const float a = ex / sum;               // attn[t][i][j]
            float o = 0.f;                          // out[t][i][w=j]
            #pragma unroll
            for (int jj = 0; jj < 8; ++jj) {
                const float ajj = __shfl(a, (lane & ~7) + jj);
                o = fmaf(ajj, vv[jj * 8 + j], o);
            }
            sScr[i * 68 + 8 * t + j] = o;           // row h=i, col 8*(s&7)+w
        }
    }
    __syncthreads();

    // ---- phase 3: y[r] = scr[h] . Wo[e]; lane = e, heads 2wg, 2wg+1 ----
    {
        const float* wo2 = &sWt[3 * WT_M + 2 * lane];
        const int h0 = t0;
        const float scrA = sScr[h0 * 68 + lane];        // lane k holds scr[h0][k]
        const float scrB = sScr[(h0 + 1) * 68 + lane];
        float y0 = 0.f, y1 = 0.f;
        #pragma unroll
        for (int kk = 0; kk < 32; ++kk) {
            const float2 w2 = *(const float2*)(wo2 + kk * PS);
            const float sa0 = rl(scrA, 2 * kk), sa1 = rl(scrA, 2 * kk + 1);
            const float sb0 = rl(scrB, 2 * kk), sb1 = rl(scrB, 2 * kk + 1);
            y0 = fmaf(w2.x, sa0, y0); y0 = fmaf(w2.y, sa1, y0);
            y1 = fmaf(w2.x, sb0, y1); y1 = fmaf(w2.y, sb1, y1);
        }
        outg[(size_t)(b * 512 + h0 * 64 + sg) * 64 + lane]       = y0;
        outg[(size_t)(b * 512 + (h0 + 1) * 64 + sg) * 64 + lane] = y1;
    }
}

extern "C" void kernel_launch(void* const* d_in, const int* in_sizes, int n_in,
                              void* d_out, int out_size, void* d_ws, size_t ws_size,
                              hipStream_t stream) {
    const float* x  = (const float*)d_in[0];
    const float* wq = (const float*)d_in[1];
    const float* wk = (const float*)d_in[2];
    const float* wv = (const float*)d_in[3];
    const float* wo = (const float*)d_in[4];
    const float* th = (const float*)d_in[5];
    float* out = (float*)d_out;
    // B=16, S=512: 16 batches x 64 octets = 1024 blocks
    qattn_fused<<<dim3(1024), dim3(256), 0, stream>>>(x, wq, wk, wv, wo, th, out);
}

// Round 7
// 73.498 us; speedup vs baseline: 1.3582x; 1.0809x over previous
//
#include <hip/hip_runtime.h>

// Analytic collapse (verified R1-R5, absmax 9.8e-4):
//   <Z_0> = c1*...*c7,  <Z_j> = c0*...*cj,  c_j = cos(t_j + theta_j)
// R6: shuffle-free design. 512 blocks x 256 thr; block = 16 tokens (2 octets);
// 64.6 KB LDS -> 2 blocks/CU co-resident, single round.
//  phase1 (all waves): lane = out elem e; 4 tokens/wave; W from swizzled LDS
//    (conflict-free b64), x broadcast via readlane; prefix products via DPP
//    row_shr scans (0 DS ops); z0 via lane-7 writes slot-0 trick.
//  phase2 (waves 0,1): row-per-lane attention, lane=(token,i): in-lane softmax,
//    k/v rows via 8-addr broadcast ds_read_b64. waves 2,3 re-stage Wo
//    concurrently (into the Wq LDS region).
//  phase3 (all waves): Wo column hoisted to 64 VGPRs; scr row broadcast via
//    readlane; coalesced stores.

#define WT  4096   // dwords per transposed W matrix (32 kk * 128)
#define SPS 66     // sP token stride (dwords)
#define SCS 17     // sScr column stride (dwords)

__device__ __forceinline__ float rl(float v, int l) {
    return __int_as_float(__builtin_amdgcn_readlane(__float_as_int(v), l));
}

// d *= dpp_row_shr<sh>(d) gated to lanes with (lane&7) >= sh
#define DPP_SHR_STEP(d, j, sh)                                                 \
    {                                                                          \
        float _t = __int_as_float(__builtin_amdgcn_update_dpp(                 \
            0x3f800000, __float_as_int(d), 0x110 + sh, 0xf, 0xf, false));      \
        d *= ((j) >= (sh)) ? _t : 1.0f;                                        \
    }

__device__ __forceinline__ float fastcos(float x) { return __cosf(x); }

__global__ __launch_bounds__(256, 2)
void qattn_fused(const float* __restrict__ xg,
                 const float* __restrict__ wqg, const float* __restrict__ wkg,
                 const float* __restrict__ wvg, const float* __restrict__ wog,
                 const float* __restrict__ thg,
                 float* __restrict__ outg)
{
    __shared__ float sWt[3 * WT];            // 48 KB  Wq,Wk,Wv (Wo re-staged into [0])
    __shared__ float sP[4 * 3 * 4 * SPS];    // 12.4 KB z values [wave][m][t][e]
    __shared__ float sScr[64 * SCS];         // 4.25 KB scrambled [col][row]

    const int tid  = threadIdx.x;
    const int lane = tid & 63;
    const int wg   = tid >> 6;
    const int j    = lane & 7;
    const int b    = blockIdx.x >> 5;
    const int grp  = blockIdx.x & 31;        // 16-token group in batch row

    // ---- stage Wq,Wk,Wv transposed + XOR-swizzled ----
    // sWt[m][kk][(2e+2kk)&127] = W[e][2kk..2kk+1]; read side is a permutation
    // of even dword pairs per kk -> conflict-free; write side <=2-way.
    {
        const float* gm[3] = {wqg, wkg, wvg};
        #pragma unroll
        for (int m = 0; m < 3; ++m) {
            #pragma unroll
            for (int r = 0; r < 4; ++r) {
                const int g = tid + 256 * r;            // float4 idx 0..1023
                const float4 v = ((const float4*)gm[m])[g];
                const int e = g >> 4, kq = g & 15;
                const int c0 = (2 * e + 4 * kq) & 127;
                const int c1 = (c0 + 2) & 127;
                *(float2*)&sWt[m * WT + 256 * kq + c0]       = make_float2(v.x, v.y);
                *(float2*)&sWt[m * WT + 256 * kq + 128 + c1] = make_float2(v.z, v.w);
            }
        }
    }
    // per-wave x rows (lane = column), 4 tokens
    float xr[4];
    {
        const float* xb = xg + ((size_t)(b * 512 + grp * 16 + wg * 4)) * 64 + lane;
        xr[0] = xb[0]; xr[1] = xb[64]; xr[2] = xb[128]; xr[3] = xb[192];
    }
    const float thf = thg[j];
    __syncthreads();

    // ---- phase 1: projections (lane = out elem e) for this wave's 4 tokens ----
    {
        float acc[3][4];
        #pragma unroll
        for (int m = 0; m < 3; ++m)
            #pragma unroll
            for (int t = 0; t < 4; ++t) acc[m][t] = 0.f;

        #pragma unroll 8
        for (int kk = 0; kk < 32; ++kk) {
            const int col = (2 * lane + 2 * kk) & 127;
            const float2 wq = *(const float2*)&sWt[0 * WT + kk * 128 + col];
            const float2 wk = *(const float2*)&sWt[1 * WT + kk * 128 + col];
            const float2 wv = *(const float2*)&sWt[2 * WT + kk * 128 + col];
            #pragma unroll
            for (int t = 0; t < 4; ++t) {
                const float x0 = rl(xr[t], 2 * kk);
                const float x1 = rl(xr[t], 2 * kk + 1);
                acc[0][t] = fmaf(wq.x, x0, fmaf(wq.y, x1, acc[0][t]));
                acc[1][t] = fmaf(wk.x, x0, fmaf(wk.y, x1, acc[1][t]));
                acc[2][t] = fmaf(wv.x, x0, fmaf(wv.y, x1, acc[2][t]));
            }
        }
        // z via DPP scans; write to sP[wg][m][t][e]
        #pragma unroll
        for (int m = 0; m < 3; ++m) {
            #pragma unroll
            for (int t = 0; t < 4; ++t) {
                const float c = fastcos(acc[m][t] + thf);
                float d = c;                      // inclusive scan (c0..cj)
                DPP_SHR_STEP(d, j, 1)
                DPP_SHR_STEP(d, j, 2)
                DPP_SHR_STEP(d, j, 4)
                float ex = (j == 0) ? 1.0f : c;   // scan excluding c0
                DPP_SHR_STEP(ex, j, 1)
                DPP_SHR_STEP(ex, j, 2)
                DPP_SHR_STEP(ex, j, 4)
                const int base = (((wg * 3 + m) * 4 + t)) * SPS + lane;
                if (j > 0)  sP[base]     = d;     // z_j = c0..cj
                if (j == 7) sP[base - 7] = ex;    // z_0 = c1..c7 into slot j=0
            }
        }
    }
    __syncthreads();

    // ---- phase 2 (waves 0,1): row-per-lane attention, 8 tokens per wave ----
    if (wg < 2) {
        const int tg = wg * 8 + (lane >> 3);     // block-local token 0..15
        const int i  = lane & 7;                 // score row (head)
        const int qb = (((tg >> 2) * 3 + 0) * 4 + (tg & 3)) * SPS;
        const int kb = qb + 4 * SPS;             // m=1
        const int vb = qb + 8 * SPS;             // m=2
        float q[8];
        #pragma unroll
        for (int c = 0; c < 4; ++c)
            *(float2*)&q[2 * c] = *(const float2*)&sP[qb + 8 * i + 2 * c];
        float p[8];
        float sum = 0.f;
        #pragma unroll
        for (int jj = 0; jj < 8; ++jj) {         // scores + exp (no max-sub: |s|<=2.83)
            float kv[8];
            #pragma unroll
            for (int c = 0; c < 4; ++c)
                *(float2*)&kv[2 * c] = *(const float2*)&sP[kb + 8 * jj + 2 * c];
            float s = q[0] * kv[0];
            #pragma unroll
            for (int w = 1; w < 8; ++w) s = fmaf(q[w], kv[w], s);
            p[jj] = __expf(s * 0.35355339059327373f);
            sum += p[jj];
        }
        const float rinv = 1.0f / sum;
        float o[8];
        #pragma unroll
        for (int w = 0; w < 8; ++w) o[w] = 0.f;
        #pragma unroll
        for (int jj = 0; jj < 8; ++jj) {
            float vv[8];
            #pragma unroll
            for (int c = 0; c < 4; ++c)
                *(float2*)&vv[2 * c] = *(const float2*)&sP[vb + 8 * jj + 2 * c];
            const float a = p[jj] * rinv;
            #pragma unroll
            for (int w = 0; w < 8; ++w) o[w] = fmaf(a, vv[w], o[w]);
        }
        // scrambled: col = 8*(tg&7)+w, row rho = i*2 + (tg>>3)
        const int rho = i * 2 + (tg >> 3);
        const int cb  = 8 * (tg & 7);
        #pragma unroll
        for (int w = 0; w < 8; ++w) sScr[(cb + w) * SCS + rho] = o[w];
    } else {
        // ---- waves 2,3: re-stage Wo into sWt[0] (Wq region, done with) ----
        const int lt = tid & 127;
        #pragma unroll
        for (int r = 0; r < 8; ++r) {
            const int g = lt + 128 * r;
            const float4 v = ((const float4*)wog)[g];
            const int e = g >> 4, kq = g & 15;
            const int c0 = (2 * e + 4 * kq) & 127;
            const int c1 = (c0 + 2) & 127;
            *(float2*)&sWt[256 * kq + c0]       = make_float2(v.x, v.y);
            *(float2*)&sWt[256 * kq + 128 + c1] = make_float2(v.z, v.w);
        }
    }
    __syncthreads();

    // ---- phase 3: y[r] = scr_row . Wo[e]; lane = e; 4 rows per wave ----
    {
        float wo[64];
        #pragma unroll
        for (int kk = 0; kk < 32; ++kk) {
            const int col = (2 * lane + 2 * kk) & 127;
            const float2 w2 = *(const float2*)&sWt[kk * 128 + col];
            wo[2 * kk] = w2.x; wo[2 * kk + 1] = w2.y;
        }
        #pragma unroll
        for (int rr = 0; rr < 4; ++rr) {
            const int rho = wg * 4 + rr;
            const float sv = sScr[lane * SCS + rho];   // lane=col holds scr[rho][col]
            float y0 = 0.f, y1 = 0.f, y2 = 0.f, y3 = 0.f;
            #pragma unroll
            for (int k = 0; k < 64; k += 4) {
                y0 = fmaf(wo[k],     rl(sv, k),     y0);
                y1 = fmaf(wo[k + 1], rl(sv, k + 1), y1);
                y2 = fmaf(wo[k + 2], rl(sv, k + 2), y2);
                y3 = fmaf(wo[k + 3], rl(sv, k + 3), y3);
            }
            const float y = (y0 + y1) + (y2 + y3);
            const int head = rho >> 1, oct = rho & 1;
            outg[((size_t)(b * 512 + head * 64 + grp * 2 + oct)) * 64 + lane] = y;
        }
    }
}

extern "C" void kernel_launch(void* const* d_in, const int* in_sizes, int n_in,
                              void* d_out, int out_size, void* d_ws, size_t ws_size,
                              hipStream_t stream) {
    const float* x  = (const float*)d_in[0];
    const float* wq = (const float*)d_in[1];
    const float* wk = (const float*)d_in[2];
    const float* wv = (const float*)d_in[3];
    const float* wo = (const float*)d_in[4];
    const float* th = (const float*)d_in[5];
    float* out = (float*)d_out;
    // B=16, S=512: 16 batches x 32 sixteen-token groups = 512 blocks
    qattn_fused<<<dim3(512), dim3(256), 0, stream>>>(x, wq, wk, wv, wo, th, out);
}